// Round 9
// baseline (9802.522 us; speedup 1.0000x reference)
//
#include <hip/hip_runtime.h>

// Persistent 2-layer LSTM, plain launch, WIDE-WG geometry.
// r8 falsified layer-split (co-residency doesn't shorten latency-bound
// chains; fp32 weight streaming is an LLC BW disaster). This round attacks
// the chain's CONTENTION terms: 128 WGs x 512 threads (8 waves), each WG =
// 32 batch rows x 32 hidden units (128 gate cols). Aggregate staged h
// traffic halves (16->8 MB/tick), rendezvous shrinks 32->16 WGs. Enabled by
// PLAIN-FP16 B fragments (dropping the lo-correction): 48 frags = ~192
// VGPR/wave -> 2 waves/SIMD so an 8-wave block is schedulable
// (launch_bounds(512,2) enforces <=256 unified regs). Precision gamble:
// A-quant alone measured 1.22e-4; +B-quant predicts ~2.5-3.5e-4 vs 3.71e-4
// threshold. MFMA count also halves (no lo passes).
// Proven r0 tick structure: one group-barrier per tick, tick t = L1 step t
// + L2 step t-1 + OUT step t-2; agent-scope LLC exchange; bounded polls.

#define NWG    128
#define NTHR   512
#define TSTEPS 512
#define HDIM   512
#define BATCH  256
#define FUT    8
#define NCOL   (TSTEPS + FUT)
#define HPLANE (BATCH * HDIM)   // one h plane (fp16 hi only)
#define FLAGSTRIDE 32           // u32s per flag line (128 B, single writer)
#define ROWB   1032             // LDS row pitch bytes (1024 + 8 pad)
#define GPITCH 132              // g-tile row pitch (floats): 128 + 4 pad
#define POLLMAX 50000u          // poll bound (~8 ms) then escape (fail fast)

typedef _Float16 half_t;
typedef _Float16 f16x8 __attribute__((ext_vector_type(8)));
typedef float    f32x4 __attribute__((ext_vector_type(4)));
typedef __attribute__((address_space(1))) const unsigned int gu32;
typedef __attribute__((address_space(3))) unsigned int su32;

struct Params {
  const float* input_t;
  const float* W_ih1; const float* b_ih1; const float* W_hh1; const float* b_hh1;
  const float* W_ih2; const float* b_ih2; const float* W_hh2; const float* b_hh2;
  const float* W_lin; const float* b_lin;
  float* out;
  unsigned* flags;     // [NWG][FLAGSTRIDE]
  float* outfeed;      // [BATCH]
  half_t* h1buf;   // [2 pp][BATCH][HDIM]
  half_t* h2buf;   // [2 pp][BATCH][HDIM]
};

// Fast exact transcendentals (validated r5/r6: absmax identical to libm).
__device__ __forceinline__ float sigm(float x) {
  const float e = __builtin_amdgcn_exp2f(-1.44269504f * x);
  return __builtin_amdgcn_rcpf(1.0f + e);
}
__device__ __forceinline__ float tanh_f(float x) {
  const float e = __builtin_amdgcn_exp2f(2.88539009f * x);
  return 1.0f - 2.0f * __builtin_amdgcn_rcpf(e + 1.0f);
}

// LLC-coherent volatile accessors (proven baseline path).
__device__ __forceinline__ f16x8 vload8(const half_t* p) {
  return *(const volatile f16x8*)p;
}
__device__ __forceinline__ void vstore2(half_t* p, half_t a, half_t b) {
  union { half_t h[2]; unsigned u; } x;
  x.h[0] = a; x.h[1] = b;
  *(volatile unsigned*)p = x.u;
}

// fp32 row -> plain fp16 fragment (8 elems)
__device__ __forceinline__ f16x8 load8_f16(const float* p) {
  const float4 a = *(const float4*)p;
  const float4 b = *(const float4*)(p + 4);
  f16x8 r;
  r[0] = (half_t)a.x; r[1] = (half_t)a.y; r[2] = (half_t)a.z; r[3] = (half_t)a.w;
  r[4] = (half_t)b.x; r[5] = (half_t)b.y; r[6] = (half_t)b.z; r[7] = (half_t)b.w;
  return r;
}

// Group barrier (16 WGs sharing a row-group). Store own flag; threads 0..15
// poll the group's flags. Bounded -> broken run fails fast, never hangs.
__device__ __forceinline__ void groupbar(unsigned* flags, int gbase, int wg, unsigned target) {
  __syncthreads();   // s_waitcnt vmcnt(0) + s_barrier => h stores at LLC
  if (threadIdx.x == 0)
    __hip_atomic_store(&flags[wg * FLAGSTRIDE], target,
                       __ATOMIC_RELAXED, __HIP_MEMORY_SCOPE_AGENT);
  if (threadIdx.x < 16) {
    unsigned iters = 0;
    while (__hip_atomic_load(&flags[(gbase + threadIdx.x) * FLAGSTRIDE],
                             __ATOMIC_RELAXED, __HIP_MEMORY_SCOPE_AGENT) < target) {
      __builtin_amdgcn_s_sleep(1);
      if (++iters > POLLMAX) break;
    }
  }
  __syncthreads();
}

__global__ void __launch_bounds__(NTHR, 2) lstm_fused(Params P) {
  const int tid  = threadIdx.x;
  const int wg   = blockIdx.x;
  const int ci   = wg & 15;    // col WG: hidden units ci*32 .. +31
  const int rb   = wg >> 4;    // row group: batch rows rb*32 .. +31
  const int gbase = wg & ~15;
  const int wv   = tid >> 6;   // wave 0..7: gate = wv>>1, sub16 = wv&1
  const int lane = tid & 63;
  const int m    = lane & 15;
  const int quad = lane >> 4;

  __shared__ __align__(16) char ldsA1[32 * ROWB];  // staged h1 rows (33 KB)
  __shared__ __align__(16) char ldsA2[32 * ROWB];  // staged h2 rows (33 KB)
  __shared__ float g1s[32 * GPITCH];               // L1 pre-acts [row][p], 16.9 KB
  __shared__ float g2s[32 * GPITCH];               // L2 pre-acts
  __shared__ float in_s[32];
  __shared__ float bias1_s[128];
  __shared__ float w1x_s[128];
  __shared__ float bias2_s[128];

  if (tid < 128) {   // p = tid: gate = p>>5, u = p&31
    const int gate = tid >> 5, u = tid & 31;
    const int gc = gate * HDIM + ci * 32 + u;
    bias1_s[tid] = P.b_ih1[gc] + P.b_hh1[gc];
    w1x_s[tid]   = P.W_ih1[gc];
    bias2_s[tid] = P.b_ih2[gc] + P.b_hh2[gc];
  }
  if (tid < 32) in_s[tid] = P.input_t[rb * 32 + tid];

  // Register-resident PLAIN-fp16 B fragments (48 frags = ~192 VGPR).
  // mfma_f32_16x16x32_f16 B layout: lane L holds B[k=(L>>4)*8+j][n=L&15].
  f16x8 B1[16];    // W_hh1
  f16x8 B2i[16];   // W_ih2
  f16x8 B2h[16];   // W_hh2
  {
    const int gc = (wv >> 1) * HDIM + ci * 32 + (wv & 1) * 16 + m;  // lane's B column
    const float* w1r  = P.W_hh1 + (size_t)gc * HDIM;
    const float* wi2r = P.W_ih2 + (size_t)gc * HDIM;
    const float* wh2r = P.W_hh2 + (size_t)gc * HDIM;
#pragma unroll
    for (int kk = 0; kk < 16; ++kk) {
      const int k0 = kk * 32 + quad * 8;
      B1[kk]  = load8_f16(w1r + k0);
      B2i[kk] = load8_f16(wi2r + k0);
      B2h[kk] = load8_f16(wh2r + k0);
    }
  }
  __syncthreads();

  float c1[2] = {0.f, 0.f}, c2[2] = {0.f, 0.f};   // cell state (fp32, registers)
  const int eb  = tid >> 4;        // elementwise: batch row 0..31
  const int eu0 = (tid & 15) * 2;  // elementwise: first of 2 units (0..30)

  // Bulk async stage: 4 rows per wave per plane (1 KB per instruction).
  auto stage = [&](const half_t* hp, char* ldst) {
#pragma unroll
    for (int r = 0; r < 4; ++r) {
      const int row = wv * 4 + r;
      const half_t* g = hp + (size_t)(rb * 32 + row) * HDIM + lane * 8;
      __builtin_amdgcn_global_load_lds((gu32*)g, (su32*)(ldst + row * ROWB), 16, 0, 0x11);
    }
  };

  // Output rows: WG (rb,ci) handles batch rows rb*32 + ci*2 + {0,1}.
  auto outrow = [&](const half_t* h2p, int col) {
    if (tid < 128) {
      const int row = rb * 32 + ci * 2 + (tid >> 6);
      const f16x8 hv = vload8(h2p + (size_t)row * HDIM + lane * 8);
      const float4 wa = *(const float4*)(P.W_lin + lane * 8);
      const float4 wb = *(const float4*)(P.W_lin + lane * 8 + 4);
      float s = (float)hv[0]*wa.x + (float)hv[1]*wa.y + (float)hv[2]*wa.z + (float)hv[3]*wa.w
              + (float)hv[4]*wb.x + (float)hv[5]*wb.y + (float)hv[6]*wb.z + (float)hv[7]*wb.w;
#pragma unroll
      for (int off = 32; off > 0; off >>= 1) s += __shfl_down(s, off);
      if (lane == 0) {
        s += P.b_lin[0];
        P.out[(size_t)row * NCOL + col] = s;
        *(volatile float*)&P.outfeed[row] = s;
      }
    }
  };

  auto tick = [&](bool doL1, bool doL2, bool doOUT, bool future, int outcol,
                  const half_t* h1rp, half_t* h1wp,
                  const half_t* h2rp, half_t* h2wp) {
    if (doL1 | doL2) stage(h1rp, ldsA1);
    if (doL2)        stage(h2rp, ldsA2);

    if (doOUT) outrow(h2rp, outcol);   // overlaps with staging in flight

    const f32x4 z4 = {0.f, 0.f, 0.f, 0.f};
    f32x4 acc1[2] = {z4, z4};
    f32x4 acc2[2] = {z4, z4};

    __syncthreads();   // staged data resident in LDS

    // A layout: lane L holds A[m=L&15][k=(L>>4)*8+j]; row tile rt: rows rt*16+m.
    const char* a1p = ldsA1 + m * ROWB + quad * 16;
    const char* a2p = ldsA2 + m * ROWB + quad * 16;

    if (doL1 | doL2) {
#pragma unroll
      for (int kk = 0; kk < 16; ++kk) {   // Phase A: A = h1[t-1]
        const int o = kk * 64;
        const f16x8 a0 = *(const f16x8*)(a1p + o);
        const f16x8 a1 = *(const f16x8*)(a1p + 16 * ROWB + o);
        if (doL1) {
          acc1[0] = __builtin_amdgcn_mfma_f32_16x16x32_f16(a0, B1[kk], acc1[0], 0, 0, 0);
          acc1[1] = __builtin_amdgcn_mfma_f32_16x16x32_f16(a1, B1[kk], acc1[1], 0, 0, 0);
        }
        if (doL2) {
          acc2[0] = __builtin_amdgcn_mfma_f32_16x16x32_f16(a0, B2i[kk], acc2[0], 0, 0, 0);
          acc2[1] = __builtin_amdgcn_mfma_f32_16x16x32_f16(a1, B2i[kk], acc2[1], 0, 0, 0);
        }
      }
    }
    if (doL2) {
#pragma unroll
      for (int kk = 0; kk < 16; ++kk) {   // Phase B: A = h2[t-2]
        const int o = kk * 64;
        const f16x8 a0 = *(const f16x8*)(a2p + o);
        const f16x8 a1 = *(const f16x8*)(a2p + 16 * ROWB + o);
        acc2[0] = __builtin_amdgcn_mfma_f32_16x16x32_f16(a0, B2h[kk], acc2[0], 0, 0, 0);
        acc2[1] = __builtin_amdgcn_mfma_f32_16x16x32_f16(a1, B2h[kk], acc2[1], 0, 0, 0);
      }
    }

    // C/D layout: col = lane&15 (tile col), row = rt*16 + quad*4 + reg.
    if (doL1) {
#pragma unroll
      for (int rt = 0; rt < 2; ++rt)
#pragma unroll
        for (int rg = 0; rg < 4; ++rg)
          g1s[(rt * 16 + quad * 4 + rg) * GPITCH + wv * 16 + m] = acc1[rt][rg];
    }
    if (doL2) {
#pragma unroll
      for (int rt = 0; rt < 2; ++rt)
#pragma unroll
        for (int rg = 0; rg < 4; ++rg)
          g2s[(rt * 16 + quad * 4 + rg) * GPITCH + wv * 16 + m] = acc2[rt][rg];
    }
    __syncthreads();

    // Elementwise: thread owns 2 (b,u) pairs; c-state stays in registers.
    float xb = 0.f;
    if (doL1) xb = future ? *(volatile const float*)&P.outfeed[rb * 32 + eb] : in_s[eb];
    if (doL1) {
      half_t hh[2];
#pragma unroll
      for (int uu = 0; uu < 2; ++uu) {
        const int u = eu0 + uu;
        const float ai = g1s[eb * GPITCH + u]      + xb * w1x_s[u]      + bias1_s[u];
        const float af = g1s[eb * GPITCH + 32 + u] + xb * w1x_s[32 + u] + bias1_s[32 + u];
        const float ag = g1s[eb * GPITCH + 64 + u] + xb * w1x_s[64 + u] + bias1_s[64 + u];
        const float ao = g1s[eb * GPITCH + 96 + u] + xb * w1x_s[96 + u] + bias1_s[96 + u];
        const float ig = sigm(ai), fg = sigm(af), gg = tanh_f(ag), og = sigm(ao);
        const float c = fg * c1[uu] + ig * gg;
        c1[uu] = c;
        hh[uu] = (half_t)(og * tanh_f(c));
      }
      vstore2(h1wp + (size_t)(rb * 32 + eb) * HDIM + ci * 32 + eu0, hh[0], hh[1]);
    }
    if (doL2) {
      half_t hh[2];
#pragma unroll
      for (int uu = 0; uu < 2; ++uu) {
        const int u = eu0 + uu;
        const float ai = g2s[eb * GPITCH + u]      + bias2_s[u];
        const float af = g2s[eb * GPITCH + 32 + u] + bias2_s[32 + u];
        const float ag = g2s[eb * GPITCH + 64 + u] + bias2_s[64 + u];
        const float ao = g2s[eb * GPITCH + 96 + u] + bias2_s[96 + u];
        const float ig = sigm(ai), fg = sigm(af), gg = tanh_f(ag), og = sigm(ao);
        const float c = fg * c2[uu] + ig * gg;
        c2[uu] = c;
        hh[uu] = (half_t)(og * tanh_f(c));
      }
      vstore2(h2wp + (size_t)(rb * 32 + eb) * HDIM + ci * 32 + eu0, hh[0], hh[1]);
    }
  };

  half_t* h1b0 = P.h1buf;  half_t* h1b1 = P.h1buf + HPLANE;
  half_t* h2b0 = P.h2buf;  half_t* h2b1 = P.h2buf + HPLANE;

  unsigned bid = 0;
  // Main pipelined ticks: tick t = L1 step t, L2 step t-1, OUT step t-2.
  for (int t = 0; t <= TSTEPS; ++t) {
    half_t* h1r = ((t + 1) & 1) ? h1b1 : h1b0;   // h1[t-1]
    half_t* h1w = (t & 1)       ? h1b1 : h1b0;   // h1[t]
    half_t* h2r = (t & 1)       ? h2b1 : h2b0;   // h2[t-2]
    half_t* h2w = ((t + 1) & 1) ? h2b1 : h2b0;   // h2[t-1]
    tick(t < TSTEPS, t >= 1, t >= 2, false, t - 2, h1r, h1w, h2r, h2w);
    groupbar(P.flags, gbase, wg, ++bid);
  }
  // Autoregressive future steps: out feeds back => 3 phases each.
  for (int k = 0; k < FUT; ++k) {
    const int s = TSTEPS + k;
    const half_t* h2last = (((s - 1) & 1)) ? h2b1 : h2b0;  // h2[s-1]
    outrow(h2last, s - 1);
    groupbar(P.flags, gbase, wg, ++bid);
    {  // L1 future step s (x = outfeed)
      half_t* h1r = (((s - 1) & 1)) ? h1b1 : h1b0;
      half_t* h1w = ((s & 1))       ? h1b1 : h1b0;
      tick(true, false, false, true, 0, h1r, h1w, h2b0, h2b0);
      groupbar(P.flags, gbase, wg, ++bid);
    }
    {  // L2 future step s (x = h1[s], hidden = h2[s-1])
      half_t* h1r = ((s & 1))       ? h1b1 : h1b0;
      half_t* h2r = (((s - 1) & 1)) ? h2b1 : h2b0;
      half_t* h2w = ((s & 1))       ? h2b1 : h2b0;
      tick(false, true, false, false, 0, h1r, h1b0, h2r, h2w);
      groupbar(P.flags, gbase, wg, ++bid);
    }
  }
  outrow((((TSTEPS + 7) & 1)) ? h2b1 : h2b0, TSTEPS + 7);
}

extern "C" void kernel_launch(void* const* d_in, const int* in_sizes, int n_in,
                              void* d_out, int out_size, void* d_ws, size_t ws_size,
                              hipStream_t stream) {
  Params P;
  P.input_t = (const float*)d_in[0];
  // d_in[1] = y : only its shape (T) matters; T hardcoded 512
  P.W_ih1 = (const float*)d_in[2];  P.b_ih1 = (const float*)d_in[3];
  P.W_hh1 = (const float*)d_in[4];  P.b_hh1 = (const float*)d_in[5];
  P.W_ih2 = (const float*)d_in[6];  P.b_ih2 = (const float*)d_in[7];
  P.W_hh2 = (const float*)d_in[8];  P.b_hh2 = (const float*)d_in[9];
  P.W_lin = (const float*)d_in[10]; P.b_lin = (const float*)d_in[11];
  P.out   = (float*)d_out;

  char* ws = (char*)d_ws;
  P.outfeed = (float*)(ws + 256);                  // 1 KB
  P.flags   = (unsigned*)(ws + 4096);              // 16 KB used
  P.h1buf   = (half_t*)(ws + 4096 + 32768);        // [2][B][H] fp16 = 512 KB
  P.h2buf   = (half_t*)(ws + 4096 + 32768 + 2 * (size_t)HPLANE * sizeof(half_t));
  const size_t need = 4096 + 32768 + 4 * (size_t)HPLANE * sizeof(half_t);  // ~1.1 MB

  (void)hipMemsetAsync(d_ws, 0, need, stream);  // zero flags+outfeed+h buffers

  // 128 blocks x 512 threads; ~101 KB LDS, <=256 unified regs (bounds) =>
  // 1 block/CU on 128 CUs, all resident.
  lstm_fused<<<dim3(NWG), dim3(NTHR), 0, stream>>>(P);
}

// Round 10
// 5950.714 us; speedup vs baseline: 1.6473x; 1.6473x over previous
//
#include <hip/hip_runtime.h>

// Persistent 2-layer LSTM, plain launch (grid=256=#CUs, 1 block/CU).
// PROVEN r0 structure (6473us): 8 row-groups x 32 col-WGs, WG = 32 batch
// rows x 64 gate cols (16 hidden units); merged h1+h2 async staging, ONE
// group-barrier per tick; agent-scope LLC exchange (volatile + atomics).
// Tick t = L1 step t + L2 step t-1 + OUT step t-2 (pipelined).
// Validated deltas applied (r5/r6/r9 evidence):
//  (1) PLAIN-fp16 B fragments -- r9 proved the lo-correction is invisible
//      (absmax == bf16 output floor either way): MFMA/tick 192->96,
//      B-regs 384->192.
//  (2) Fast exact transcendentals (v_exp_f32+v_rcp_f32; r5/r6: absmax
//      identical to libm).
//  (3) Bounded barrier polls (33ms failsafe): broken run fails fast with
//      counters, never hangs a container (r1 lesson).
// Geometry restructurings all falsified: r6 split-flags (null), r8
// layer-split (-27%), r9 wide-WG (-50%). This is consolidation on the
// best-known structure.

#define WGS    256
#define NTHR   256
#define TSTEPS 512
#define HDIM   512
#define BATCH  256
#define FUT    8
#define NCOL   (TSTEPS + FUT)
#define HPLANE (BATCH * HDIM)   // one h plane (fp16 hi only)
#define FLAGSTRIDE 32           // u32s per flag line (128 B)
#define ROWB   1032             // LDS row pitch bytes (1024 + 8 pad)
#define GPITCH 68               // g-tile row pitch (floats)
#define POLLMAX 200000u         // poll bound (~33 ms) then escape (fail fast)

typedef _Float16 half_t;
typedef _Float16 f16x8 __attribute__((ext_vector_type(8)));
typedef float    f32x4 __attribute__((ext_vector_type(4)));
typedef __attribute__((address_space(1))) const unsigned int gu32;
typedef __attribute__((address_space(3))) unsigned int su32;

struct Params {
  const float* input_t;
  const float* W_ih1; const float* b_ih1; const float* W_hh1; const float* b_hh1;
  const float* W_ih2; const float* b_ih2; const float* W_hh2; const float* b_hh2;
  const float* W_lin; const float* b_lin;
  float* out;
  unsigned* flags;     // [WGS][FLAGSTRIDE]
  float* outfeed;      // [BATCH]
  half_t* h1buf;   // [2 pp][BATCH][HDIM]
  half_t* h2buf;   // [2 pp][BATCH][HDIM]
};

// Fast exact transcendentals (validated r5/r6: absmax identical to libm).
__device__ __forceinline__ float sigm(float x) {
  const float e = __builtin_amdgcn_exp2f(-1.44269504f * x);   // e^{-x}
  return __builtin_amdgcn_rcpf(1.0f + e);
}
__device__ __forceinline__ float tanh_f(float x) {
  const float e = __builtin_amdgcn_exp2f(2.88539009f * x);    // e^{2x}
  return 1.0f - 2.0f * __builtin_amdgcn_rcpf(e + 1.0f);
}

// LLC-coherent volatile accessors (proven baseline path).
__device__ __forceinline__ f16x8 vload8(const half_t* p) {
  return *(const volatile f16x8*)p;
}
__device__ __forceinline__ void vstore2(half_t* p, half_t a, half_t b) {
  union { half_t h[2]; unsigned u; } x;
  x.h[0] = a; x.h[1] = b;
  *(volatile unsigned*)p = x.u;
}

// fp32 row -> plain fp16 fragment (8 elems); r9 proved lo-correction unneeded.
__device__ __forceinline__ f16x8 load8_f16(const float* p) {
  const float4 a = *(const float4*)p;
  const float4 b = *(const float4*)(p + 4);
  f16x8 r;
  r[0] = (half_t)a.x; r[1] = (half_t)a.y; r[2] = (half_t)a.z; r[3] = (half_t)a.w;
  r[4] = (half_t)b.x; r[5] = (half_t)b.y; r[6] = (half_t)b.z; r[7] = (half_t)b.w;
  return r;
}

// Group barrier (32 WGs sharing a row-group). Store own flag (single writer
// per 128B line); threads 0..31 poll the group's flags; volatile h stores
// are at the LLC when __syncthreads' vmcnt(0) drain completes.
__device__ __forceinline__ void groupbar(unsigned* flags, int gbase, int wg, unsigned target) {
  __syncthreads();   // s_waitcnt vmcnt(0) + s_barrier
  if (threadIdx.x == 0)
    __hip_atomic_store(&flags[wg * FLAGSTRIDE], target,
                       __ATOMIC_RELAXED, __HIP_MEMORY_SCOPE_AGENT);
  if (threadIdx.x < 32) {
    unsigned iters = 0;
    while (__hip_atomic_load(&flags[(gbase + threadIdx.x) * FLAGSTRIDE],
                             __ATOMIC_RELAXED, __HIP_MEMORY_SCOPE_AGENT) < target) {
      __builtin_amdgcn_s_sleep(1);
      if (++iters > POLLMAX) break;  // bounded failsafe: fail fast, never hang
    }
  }
  __syncthreads();
}

__global__ void __launch_bounds__(NTHR, 1) lstm_fused(Params P) {
  const int tid  = threadIdx.x;
  const int wg   = blockIdx.x;
  const int cg   = wg & 31;    // col group: hidden units cg*16 .. +15
  const int rb   = wg >> 5;    // row group: batch rows rb*32 .. +31
  const int wv   = tid >> 6;   // wave 0..3 == gate index (i,f,g,o)
  const int lane = tid & 63;
  const int m    = lane & 15;
  const int quad = lane >> 4;

  __shared__ __align__(16) char ldsA1[32 * ROWB];  // staged h1 rows (33 KB)
  __shared__ __align__(16) char ldsA2[32 * ROWB];  // staged h2 rows (33 KB)
  __shared__ float g1s[32 * GPITCH];               // L1 gate pre-acts [row][p]
  __shared__ float g2s[32 * GPITCH];               // L2 gate pre-acts
  __shared__ float in_s[32];
  __shared__ float bias1_s[64];
  __shared__ float w1x_s[64];
  __shared__ float bias2_s[64];

  if (tid < 64) {   // p = tid: gate = p>>4, ul = p&15
    const int gate = tid >> 4, ul = tid & 15;
    const int gc = gate * HDIM + cg * 16 + ul;
    bias1_s[tid] = P.b_ih1[gc] + P.b_hh1[gc];
    w1x_s[tid]   = P.W_ih1[gc];
    bias2_s[tid] = P.b_ih2[gc] + P.b_hh2[gc];
  }
  if (tid < 32) in_s[tid] = P.input_t[rb * 32 + tid];

  // Register-resident PLAIN-fp16 B fragments (48 frags = 192 VGPR).
  // mfma_f32_16x16x32_f16 B layout: lane L holds B[k=(L>>4)*8+j][n=L&15].
  f16x8 B1[16];    // W_hh1
  f16x8 B2[32];    // [0..15]=W_ih2, [16..31]=W_hh2
  {
    const int gc = wv * HDIM + cg * 16 + m;   // this lane's B column
    const float* w1r  = P.W_hh1 + (size_t)gc * HDIM;
    const float* wi2r = P.W_ih2 + (size_t)gc * HDIM;
    const float* wh2r = P.W_hh2 + (size_t)gc * HDIM;
#pragma unroll
    for (int kk = 0; kk < 16; ++kk) {
      const int k0 = kk * 32 + quad * 8;
      B1[kk]      = load8_f16(w1r + k0);
      B2[kk]      = load8_f16(wi2r + k0);
      B2[16 + kk] = load8_f16(wh2r + k0);
    }
  }
  __syncthreads();

  float c1[2] = {0.f, 0.f}, c2[2] = {0.f, 0.f};   // cell state (fp32, registers)
  const int eb  = tid >> 3;        // elementwise: batch row 0..31
  const int eu0 = (tid & 7) * 2;   // elementwise: first of 2 units (0..14)

  // Bulk async stage: 8 rows per wave per plane (1024 B per instruction).
  auto stage = [&](const half_t* hp, char* ldst) {
#pragma unroll
    for (int r = 0; r < 8; ++r) {
      const int row = wv * 8 + r;
      const half_t* g = hp + (size_t)(rb * 32 + row) * HDIM + lane * 8;
      __builtin_amdgcn_global_load_lds((gu32*)g, (su32*)(ldst + row * ROWB), 16, 0, 0x11);
    }
  };

  // Output row: WG wg handles batch row wg (row wg is inside its own group).
  auto outrow = [&](const half_t* h2p, int col) {
    if (tid < 64) {
      const f16x8 hv = vload8(h2p + (size_t)wg * HDIM + lane * 8);
      const float4 wa = *(const float4*)(P.W_lin + lane * 8);
      const float4 wb = *(const float4*)(P.W_lin + lane * 8 + 4);
      float s = (float)hv[0]*wa.x + (float)hv[1]*wa.y + (float)hv[2]*wa.z + (float)hv[3]*wa.w
              + (float)hv[4]*wb.x + (float)hv[5]*wb.y + (float)hv[6]*wb.z + (float)hv[7]*wb.w;
#pragma unroll
      for (int off = 32; off > 0; off >>= 1) s += __shfl_down(s, off);
      if (lane == 0) {
        s += P.b_lin[0];
        P.out[(size_t)wg * NCOL + col] = s;
        *(volatile float*)&P.outfeed[wg] = s;
      }
    }
  };

  auto tick = [&](bool doL1, bool doL2, bool doOUT, bool future, int outcol,
                  const half_t* h1rp, half_t* h1wp,
                  const half_t* h2rp, half_t* h2wp) {
    // Merged staging: both phases issued up front, one vmcnt(0)+barrier.
    if (doL1 | doL2) stage(h1rp, ldsA1);
    if (doL2)        stage(h2rp, ldsA2);

    if (doOUT) outrow(h2rp, outcol);   // overlaps with staging in flight

    const f32x4 z4 = {0.f, 0.f, 0.f, 0.f};
    f32x4 acc1[2] = {z4, z4};
    f32x4 acc2[2] = {z4, z4};

    __syncthreads();   // staged data resident in LDS

    // A layout: lane L holds A[m=L&15][k=(L>>4)*8+j]; row tile rt: rows rt*16+m.
    const char* a1p = ldsA1 + m * ROWB + quad * 16;
    const char* a2p = ldsA2 + m * ROWB + quad * 16;

    if (doL1 | doL2) {
#pragma unroll
      for (int kk = 0; kk < 16; ++kk) {   // Phase A: A = h1[t-1]
        const int o = kk * 64;
        const f16x8 a0 = *(const f16x8*)(a1p + o);
        const f16x8 a1 = *(const f16x8*)(a1p + 16 * ROWB + o);
        if (doL1) {
          acc1[0] = __builtin_amdgcn_mfma_f32_16x16x32_f16(a0, B1[kk], acc1[0], 0, 0, 0);
          acc1[1] = __builtin_amdgcn_mfma_f32_16x16x32_f16(a1, B1[kk], acc1[1], 0, 0, 0);
        }
        if (doL2) {
          acc2[0] = __builtin_amdgcn_mfma_f32_16x16x32_f16(a0, B2[kk], acc2[0], 0, 0, 0);
          acc2[1] = __builtin_amdgcn_mfma_f32_16x16x32_f16(a1, B2[kk], acc2[1], 0, 0, 0);
        }
      }
    }
    if (doL2) {
#pragma unroll
      for (int kk = 0; kk < 16; ++kk) {   // Phase B: A = h2[t-2]
        const int o = kk * 64;
        const f16x8 a0 = *(const f16x8*)(a2p + o);
        const f16x8 a1 = *(const f16x8*)(a2p + 16 * ROWB + o);
        acc2[0] = __builtin_amdgcn_mfma_f32_16x16x32_f16(a0, B2[16 + kk], acc2[0], 0, 0, 0);
        acc2[1] = __builtin_amdgcn_mfma_f32_16x16x32_f16(a1, B2[16 + kk], acc2[1], 0, 0, 0);
      }
    }

    // C/D layout: col = lane&15 (tile col), row = rt*16 + quad*4 + reg.
    if (doL1) {
#pragma unroll
      for (int rt = 0; rt < 2; ++rt)
#pragma unroll
        for (int rg = 0; rg < 4; ++rg)
          g1s[(rt * 16 + quad * 4 + rg) * GPITCH + wv * 16 + m] = acc1[rt][rg];
    }
    if (doL2) {
#pragma unroll
      for (int rt = 0; rt < 2; ++rt)
#pragma unroll
        for (int rg = 0; rg < 4; ++rg)
          g2s[(rt * 16 + quad * 4 + rg) * GPITCH + wv * 16 + m] = acc2[rt][rg];
    }
    __syncthreads();

    // Elementwise: thread owns 2 (b,u) pairs; c-state stays in registers.
    float xb = 0.f;
    if (doL1) xb = future ? *(volatile const float*)&P.outfeed[rb * 32 + eb] : in_s[eb];
    if (doL1) {
      half_t hh[2];
#pragma unroll
      for (int uu = 0; uu < 2; ++uu) {
        const int u = eu0 + uu;
        const float ai = g1s[eb * GPITCH + u]      + xb * w1x_s[u]      + bias1_s[u];
        const float af = g1s[eb * GPITCH + 16 + u] + xb * w1x_s[16 + u] + bias1_s[16 + u];
        const float ag = g1s[eb * GPITCH + 32 + u] + xb * w1x_s[32 + u] + bias1_s[32 + u];
        const float ao = g1s[eb * GPITCH + 48 + u] + xb * w1x_s[48 + u] + bias1_s[48 + u];
        const float ig = sigm(ai), fg = sigm(af), gg = tanh_f(ag), og = sigm(ao);
        const float c = fg * c1[uu] + ig * gg;
        c1[uu] = c;
        hh[uu] = (half_t)(og * tanh_f(c));
      }
      vstore2(h1wp + (size_t)(rb * 32 + eb) * HDIM + cg * 16 + eu0, hh[0], hh[1]);
    }
    if (doL2) {
      half_t hh[2];
#pragma unroll
      for (int uu = 0; uu < 2; ++uu) {
        const int u = eu0 + uu;
        const float ai = g2s[eb * GPITCH + u]      + bias2_s[u];
        const float af = g2s[eb * GPITCH + 16 + u] + bias2_s[16 + u];
        const float ag = g2s[eb * GPITCH + 32 + u] + bias2_s[32 + u];
        const float ao = g2s[eb * GPITCH + 48 + u] + bias2_s[48 + u];
        const float ig = sigm(ai), fg = sigm(af), gg = tanh_f(ag), og = sigm(ao);
        const float c = fg * c2[uu] + ig * gg;
        c2[uu] = c;
        hh[uu] = (half_t)(og * tanh_f(c));
      }
      vstore2(h2wp + (size_t)(rb * 32 + eb) * HDIM + cg * 16 + eu0, hh[0], hh[1]);
    }
  };

  half_t* h1b0 = P.h1buf;  half_t* h1b1 = P.h1buf + HPLANE;
  half_t* h2b0 = P.h2buf;  half_t* h2b1 = P.h2buf + HPLANE;
  const int gbase = wg & ~31;

  unsigned bid = 0;
  // Main pipelined ticks: tick t = L1 step t, L2 step t-1, OUT step t-2.
  for (int t = 0; t <= TSTEPS; ++t) {
    half_t* h1r = ((t + 1) & 1) ? h1b1 : h1b0;   // h1[t-1]
    half_t* h1w = (t & 1)       ? h1b1 : h1b0;   // h1[t]
    half_t* h2r = (t & 1)       ? h2b1 : h2b0;   // h2[t-2]
    half_t* h2w = ((t + 1) & 1) ? h2b1 : h2b0;   // h2[t-1]
    tick(t < TSTEPS, t >= 1, t >= 2, false, t - 2, h1r, h1w, h2r, h2w);
    groupbar(P.flags, gbase, wg, ++bid);
  }
  // Autoregressive future steps: out feeds back => 3 phases each.
  for (int k = 0; k < FUT; ++k) {
    const int s = TSTEPS + k;
    const half_t* h2last = (((s - 1) & 1)) ? h2b1 : h2b0;  // h2[s-1]
    outrow(h2last, s - 1);
    groupbar(P.flags, gbase, wg, ++bid);
    {  // L1 future step s (x = outfeed)
      half_t* h1r = (((s - 1) & 1)) ? h1b1 : h1b0;
      half_t* h1w = ((s & 1))       ? h1b1 : h1b0;
      tick(true, false, false, true, 0, h1r, h1w, h2b0, h2b0);
      groupbar(P.flags, gbase, wg, ++bid);
    }
    {  // L2 future step s (x = h1[s], hidden = h2[s-1])
      half_t* h1r = ((s & 1))       ? h1b1 : h1b0;
      half_t* h2r = (((s - 1) & 1)) ? h2b1 : h2b0;
      half_t* h2w = ((s & 1))       ? h2b1 : h2b0;
      tick(false, true, false, false, 0, h1r, h1b0, h2r, h2w);
      groupbar(P.flags, gbase, wg, ++bid);
    }
  }
  outrow((((TSTEPS + 7) & 1)) ? h2b1 : h2b0, TSTEPS + 7);
}

extern "C" void kernel_launch(void* const* d_in, const int* in_sizes, int n_in,
                              void* d_out, int out_size, void* d_ws, size_t ws_size,
                              hipStream_t stream) {
  Params P;
  P.input_t = (const float*)d_in[0];
  // d_in[1] = y : only its shape (T) matters; T hardcoded 512
  P.W_ih1 = (const float*)d_in[2];  P.b_ih1 = (const float*)d_in[3];
  P.W_hh1 = (const float*)d_in[4];  P.b_hh1 = (const float*)d_in[5];
  P.W_ih2 = (const float*)d_in[6];  P.b_ih2 = (const float*)d_in[7];
  P.W_hh2 = (const float*)d_in[8];  P.b_hh2 = (const float*)d_in[9];
  P.W_lin = (const float*)d_in[10]; P.b_lin = (const float*)d_in[11];
  P.out   = (float*)d_out;

  char* ws = (char*)d_ws;
  P.outfeed = (float*)(ws + 256);                  // 1 KB
  P.flags   = (unsigned*)(ws + 4096);              // 32 KB
  P.h1buf   = (half_t*)(ws + 4096 + 32768);        // [2][B][H] fp16 = 512 KB
  P.h2buf   = (half_t*)(ws + 4096 + 32768 + 2 * (size_t)HPLANE * sizeof(half_t));
  const size_t need = 4096 + 32768 + 4 * (size_t)HPLANE * sizeof(half_t);  // ~1.1 MB

  (void)hipMemsetAsync(d_ws, 0, need, stream);  // zero flags+outfeed+h buffers

  // PLAIN launch: grid == 256 CUs, 1 block/CU by resources => all resident.
  lstm_fused<<<dim3(WGS), dim3(NTHR), 0, stream>>>(P);
}

// Round 11
// 3136.842 us; speedup vs baseline: 3.1250x; 1.8970x over previous
//
#include <hip/hip_runtime.h>

// Persistent 2-layer LSTM, plain launch (grid=256=#CUs, 1 block/CU).
// PROVEN structure (r10, 5951us): 8 row-groups x 32 col-WGs, WG = 32 batch
// rows x 64 gate cols (16 hidden units); merged h1+h2 async staging, ONE
// group-barrier per tick; agent-scope LLC exchange; plain-fp16 B fragments
// (r9: lo-correction invisible); fast exp2 transcendentals (r5/r6).
// This round, surgical only:
//  (1) ROWB 1032->1040: row stride 258->260 dwords; 258=2 mod 32 made every
//      ds_read_b128 4-way bank-conflicted (lane (m,q) -> bank 2(m+2q), even
//      banks only); 260=4 mod 32 gives banks 4(m+q) -> exactly 2 lanes/bank
//      = free (m136). Predicts SQ_LDS_BANK_CONFLICT 1.7e7 -> <3e6.
//  (2) GPITCH 68->67: odd dword stride spreads elementwise g-reads ~2-way.
//  (3) Early-h1 store: PhaseA -> writeg1 -> sync -> ew1(h1 store) ->
//      PhaseB -> writeg2 -> sync -> ew2 -> barrier. h1's scattered stores
//      drain under PhaseB MFMAs + ew2 VALU instead of stacking at the
//      barrier's vmcnt(0).

#define WGS    256
#define NTHR   256
#define TSTEPS 512
#define HDIM   512
#define BATCH  256
#define FUT    8
#define NCOL   (TSTEPS + FUT)
#define HPLANE (BATCH * HDIM)   // one h plane (fp16 hi only)
#define FLAGSTRIDE 32           // u32s per flag line (128 B)
#define ROWB   1040             // LDS row pitch bytes (1024 + 16 pad; 260 dw = 4 mod 32)
#define GPITCH 67               // g-tile row pitch (floats, odd stride)
#define POLLMAX 200000u         // poll bound (~33 ms) then escape (fail fast)

typedef _Float16 half_t;
typedef _Float16 f16x8 __attribute__((ext_vector_type(8)));
typedef float    f32x4 __attribute__((ext_vector_type(4)));
typedef __attribute__((address_space(1))) const unsigned int gu32;
typedef __attribute__((address_space(3))) unsigned int su32;

struct Params {
  const float* input_t;
  const float* W_ih1; const float* b_ih1; const float* W_hh1; const float* b_hh1;
  const float* W_ih2; const float* b_ih2; const float* W_hh2; const float* b_hh2;
  const float* W_lin; const float* b_lin;
  float* out;
  unsigned* flags;     // [WGS][FLAGSTRIDE]
  float* outfeed;      // [BATCH]
  half_t* h1buf;   // [2 pp][BATCH][HDIM]
  half_t* h2buf;   // [2 pp][BATCH][HDIM]
};

// Fast exact transcendentals (validated r5/r6: absmax identical to libm).
__device__ __forceinline__ float sigm(float x) {
  const float e = __builtin_amdgcn_exp2f(-1.44269504f * x);   // e^{-x}
  return __builtin_amdgcn_rcpf(1.0f + e);
}
__device__ __forceinline__ float tanh_f(float x) {
  const float e = __builtin_amdgcn_exp2f(2.88539009f * x);    // e^{2x}
  return 1.0f - 2.0f * __builtin_amdgcn_rcpf(e + 1.0f);
}

// LLC-coherent volatile accessors (proven baseline path).
__device__ __forceinline__ f16x8 vload8(const half_t* p) {
  return *(const volatile f16x8*)p;
}
__device__ __forceinline__ void vstore2(half_t* p, half_t a, half_t b) {
  union { half_t h[2]; unsigned u; } x;
  x.h[0] = a; x.h[1] = b;
  *(volatile unsigned*)p = x.u;
}

// fp32 row -> plain fp16 fragment (8 elems); r9 proved lo-correction unneeded.
__device__ __forceinline__ f16x8 load8_f16(const float* p) {
  const float4 a = *(const float4*)p;
  const float4 b = *(const float4*)(p + 4);
  f16x8 r;
  r[0] = (half_t)a.x; r[1] = (half_t)a.y; r[2] = (half_t)a.z; r[3] = (half_t)a.w;
  r[4] = (half_t)b.x; r[5] = (half_t)b.y; r[6] = (half_t)b.z; r[7] = (half_t)b.w;
  return r;
}

// Group barrier (32 WGs sharing a row-group). Store own flag (single writer
// per 128B line); threads 0..31 poll the group's flags; volatile h stores
// are at the LLC when __syncthreads' vmcnt(0) drain completes.
__device__ __forceinline__ void groupbar(unsigned* flags, int gbase, int wg, unsigned target) {
  __syncthreads();   // s_waitcnt vmcnt(0) + s_barrier
  if (threadIdx.x == 0)
    __hip_atomic_store(&flags[wg * FLAGSTRIDE], target,
                       __ATOMIC_RELAXED, __HIP_MEMORY_SCOPE_AGENT);
  if (threadIdx.x < 32) {
    unsigned iters = 0;
    while (__hip_atomic_load(&flags[(gbase + threadIdx.x) * FLAGSTRIDE],
                             __ATOMIC_RELAXED, __HIP_MEMORY_SCOPE_AGENT) < target) {
      __builtin_amdgcn_s_sleep(1);
      if (++iters > POLLMAX) break;  // bounded failsafe: fail fast, never hang
    }
  }
  __syncthreads();
}

__global__ void __launch_bounds__(NTHR, 1) lstm_fused(Params P) {
  const int tid  = threadIdx.x;
  const int wg   = blockIdx.x;
  const int cg   = wg & 31;    // col group: hidden units cg*16 .. +15
  const int rb   = wg >> 5;    // row group: batch rows rb*32 .. +31
  const int wv   = tid >> 6;   // wave 0..3 == gate index (i,f,g,o)
  const int lane = tid & 63;
  const int m    = lane & 15;
  const int quad = lane >> 4;

  __shared__ __align__(16) char ldsA1[32 * ROWB];  // staged h1 rows (32.5 KB)
  __shared__ __align__(16) char ldsA2[32 * ROWB];  // staged h2 rows (32.5 KB)
  __shared__ float g1s[32 * GPITCH];               // L1 gate pre-acts [row][p]
  __shared__ float g2s[32 * GPITCH];               // L2 gate pre-acts
  __shared__ float in_s[32];
  __shared__ float bias1_s[64];
  __shared__ float w1x_s[64];
  __shared__ float bias2_s[64];

  if (tid < 64) {   // p = tid: gate = p>>4, ul = p&15
    const int gate = tid >> 4, ul = tid & 15;
    const int gc = gate * HDIM + cg * 16 + ul;
    bias1_s[tid] = P.b_ih1[gc] + P.b_hh1[gc];
    w1x_s[tid]   = P.W_ih1[gc];
    bias2_s[tid] = P.b_ih2[gc] + P.b_hh2[gc];
  }
  if (tid < 32) in_s[tid] = P.input_t[rb * 32 + tid];

  // Register-resident PLAIN-fp16 B fragments (48 frags = 192 VGPR).
  // mfma_f32_16x16x32_f16 B layout: lane L holds B[k=(L>>4)*8+j][n=L&15].
  f16x8 B1[16];    // W_hh1
  f16x8 B2[32];    // [0..15]=W_ih2, [16..31]=W_hh2
  {
    const int gc = wv * HDIM + cg * 16 + m;   // this lane's B column
    const float* w1r  = P.W_hh1 + (size_t)gc * HDIM;
    const float* wi2r = P.W_ih2 + (size_t)gc * HDIM;
    const float* wh2r = P.W_hh2 + (size_t)gc * HDIM;
#pragma unroll
    for (int kk = 0; kk < 16; ++kk) {
      const int k0 = kk * 32 + quad * 8;
      B1[kk]      = load8_f16(w1r + k0);
      B2[kk]      = load8_f16(wi2r + k0);
      B2[16 + kk] = load8_f16(wh2r + k0);
    }
  }
  __syncthreads();

  float c1[2] = {0.f, 0.f}, c2[2] = {0.f, 0.f};   // cell state (fp32, registers)
  const int eb  = tid >> 3;        // elementwise: batch row 0..31
  const int eu0 = (tid & 7) * 2;   // elementwise: first of 2 units (0..14)

  // Bulk async stage: 8 rows per wave per plane (1024 B per instruction).
  auto stage = [&](const half_t* hp, char* ldst) {
#pragma unroll
    for (int r = 0; r < 8; ++r) {
      const int row = wv * 8 + r;
      const half_t* g = hp + (size_t)(rb * 32 + row) * HDIM + lane * 8;
      __builtin_amdgcn_global_load_lds((gu32*)g, (su32*)(ldst + row * ROWB), 16, 0, 0x11);
    }
  };

  // Output row: WG wg handles batch row wg (row wg is inside its own group).
  auto outrow = [&](const half_t* h2p, int col) {
    if (tid < 64) {
      const f16x8 hv = vload8(h2p + (size_t)wg * HDIM + lane * 8);
      const float4 wa = *(const float4*)(P.W_lin + lane * 8);
      const float4 wb = *(const float4*)(P.W_lin + lane * 8 + 4);
      float s = (float)hv[0]*wa.x + (float)hv[1]*wa.y + (float)hv[2]*wa.z + (float)hv[3]*wa.w
              + (float)hv[4]*wb.x + (float)hv[5]*wb.y + (float)hv[6]*wb.z + (float)hv[7]*wb.w;
#pragma unroll
      for (int off = 32; off > 0; off >>= 1) s += __shfl_down(s, off);
      if (lane == 0) {
        s += P.b_lin[0];
        P.out[(size_t)wg * NCOL + col] = s;
        *(volatile float*)&P.outfeed[wg] = s;
      }
    }
  };

  auto tick = [&](bool doL1, bool doL2, bool doOUT, bool future, int outcol,
                  const half_t* h1rp, half_t* h1wp,
                  const half_t* h2rp, half_t* h2wp) {
    // Merged staging: both phases issued up front, one vmcnt(0)+barrier.
    if (doL1 | doL2) stage(h1rp, ldsA1);
    if (doL2)        stage(h2rp, ldsA2);

    if (doOUT) outrow(h2rp, outcol);   // overlaps with staging in flight

    const f32x4 z4 = {0.f, 0.f, 0.f, 0.f};
    f32x4 acc1[2] = {z4, z4};
    f32x4 acc2[2] = {z4, z4};

    __syncthreads();   // staged data resident in LDS

    // A layout: lane L holds A[m=L&15][k=(L>>4)*8+j]; row tile rt: rows rt*16+m.
    const char* a1p = ldsA1 + m * ROWB + quad * 16;
    const char* a2p = ldsA2 + m * ROWB + quad * 16;

    if (doL1 | doL2) {
#pragma unroll
      for (int kk = 0; kk < 16; ++kk) {   // Phase A: A = h1[t-1]
        const int o = kk * 64;
        const f16x8 a0 = *(const f16x8*)(a1p + o);
        const f16x8 a1 = *(const f16x8*)(a1p + 16 * ROWB + o);
        if (doL1) {
          acc1[0] = __builtin_amdgcn_mfma_f32_16x16x32_f16(a0, B1[kk], acc1[0], 0, 0, 0);
          acc1[1] = __builtin_amdgcn_mfma_f32_16x16x32_f16(a1, B1[kk], acc1[1], 0, 0, 0);
        }
        if (doL2) {
          acc2[0] = __builtin_amdgcn_mfma_f32_16x16x32_f16(a0, B2[kk], acc2[0], 0, 0, 0);
          acc2[1] = __builtin_amdgcn_mfma_f32_16x16x32_f16(a1, B2[kk], acc2[1], 0, 0, 0);
        }
      }
    }

    // Early L1 finish: write g1s, sync, elementwise + h1 store FIRST so the
    // scattered h1 stores drain under Phase B MFMAs + ew2 VALU.
    if (doL1) {
#pragma unroll
      for (int rt = 0; rt < 2; ++rt)
#pragma unroll
        for (int rg = 0; rg < 4; ++rg)
          g1s[(rt * 16 + quad * 4 + rg) * GPITCH + wv * 16 + m] = acc1[rt][rg];
    }
    __syncthreads();

    if (doL1) {
      float xb = future ? *(volatile const float*)&P.outfeed[rb * 32 + eb] : in_s[eb];
      half_t hh[2];
#pragma unroll
      for (int uu = 0; uu < 2; ++uu) {
        const int u = eu0 + uu;
        const float ai = g1s[eb * GPITCH + u]      + xb * w1x_s[u]      + bias1_s[u];
        const float af = g1s[eb * GPITCH + 16 + u] + xb * w1x_s[16 + u] + bias1_s[16 + u];
        const float ag = g1s[eb * GPITCH + 32 + u] + xb * w1x_s[32 + u] + bias1_s[32 + u];
        const float ao = g1s[eb * GPITCH + 48 + u] + xb * w1x_s[48 + u] + bias1_s[48 + u];
        const float ig = sigm(ai), fg = sigm(af), gg = tanh_f(ag), og = sigm(ao);
        const float c = fg * c1[uu] + ig * gg;
        c1[uu] = c;
        hh[uu] = (half_t)(og * tanh_f(c));
      }
      vstore2(h1wp + (size_t)(rb * 32 + eb) * HDIM + cg * 16 + eu0, hh[0], hh[1]);
    }

    if (doL2) {
#pragma unroll
      for (int kk = 0; kk < 16; ++kk) {   // Phase B: A = h2[t-2]
        const int o = kk * 64;
        const f16x8 a0 = *(const f16x8*)(a2p + o);
        const f16x8 a1 = *(const f16x8*)(a2p + 16 * ROWB + o);
        acc2[0] = __builtin_amdgcn_mfma_f32_16x16x32_f16(a0, B2[16 + kk], acc2[0], 0, 0, 0);
        acc2[1] = __builtin_amdgcn_mfma_f32_16x16x32_f16(a1, B2[16 + kk], acc2[1], 0, 0, 0);
      }
#pragma unroll
      for (int rt = 0; rt < 2; ++rt)
#pragma unroll
        for (int rg = 0; rg < 4; ++rg)
          g2s[(rt * 16 + quad * 4 + rg) * GPITCH + wv * 16 + m] = acc2[rt][rg];
    }
    __syncthreads();

    if (doL2) {
      half_t hh[2];
#pragma unroll
      for (int uu = 0; uu < 2; ++uu) {
        const int u = eu0 + uu;
        const float ai = g2s[eb * GPITCH + u]      + bias2_s[u];
        const float af = g2s[eb * GPITCH + 16 + u] + bias2_s[16 + u];
        const float ag = g2s[eb * GPITCH + 32 + u] + bias2_s[32 + u];
        const float ao = g2s[eb * GPITCH + 48 + u] + bias2_s[48 + u];
        const float ig = sigm(ai), fg = sigm(af), gg = tanh_f(ag), og = sigm(ao);
        const float c = fg * c2[uu] + ig * gg;
        c2[uu] = c;
        hh[uu] = (half_t)(og * tanh_f(c));
      }
      vstore2(h2wp + (size_t)(rb * 32 + eb) * HDIM + cg * 16 + eu0, hh[0], hh[1]);
    }
  };

  half_t* h1b0 = P.h1buf;  half_t* h1b1 = P.h1buf + HPLANE;
  half_t* h2b0 = P.h2buf;  half_t* h2b1 = P.h2buf + HPLANE;
  const int gbase = wg & ~31;

  unsigned bid = 0;
  // Main pipelined ticks: tick t = L1 step t, L2 step t-1, OUT step t-2.
  for (int t = 0; t <= TSTEPS; ++t) {
    half_t* h1r = ((t + 1) & 1) ? h1b1 : h1b0;   // h1[t-1]
    half_t* h1w = (t & 1)       ? h1b1 : h1b0;   // h1[t]
    half_t* h2r = (t & 1)       ? h2b1 : h2b0;   // h2[t-2]
    half_t* h2w = ((t + 1) & 1) ? h2b1 : h2b0;   // h2[t-1]
    tick(t < TSTEPS, t >= 1, t >= 2, false, t - 2, h1r, h1w, h2r, h2w);
    groupbar(P.flags, gbase, wg, ++bid);
  }
  // Autoregressive future steps: out feeds back => 3 phases each.
  for (int k = 0; k < FUT; ++k) {
    const int s = TSTEPS + k;
    const half_t* h2last = (((s - 1) & 1)) ? h2b1 : h2b0;  // h2[s-1]
    outrow(h2last, s - 1);
    groupbar(P.flags, gbase, wg, ++bid);
    {  // L1 future step s (x = outfeed)
      half_t* h1r = (((s - 1) & 1)) ? h1b1 : h1b0;
      half_t* h1w = ((s & 1))       ? h1b1 : h1b0;
      tick(true, false, false, true, 0, h1r, h1w, h2b0, h2b0);
      groupbar(P.flags, gbase, wg, ++bid);
    }
    {  // L2 future step s (x = h1[s], hidden = h2[s-1])
      half_t* h1r = ((s & 1))       ? h1b1 : h1b0;
      half_t* h2r = (((s - 1) & 1)) ? h2b1 : h2b0;
      half_t* h2w = ((s & 1))       ? h2b1 : h2b0;
      tick(false, true, false, false, 0, h1r, h1b0, h2r, h2w);
      groupbar(P.flags, gbase, wg, ++bid);
    }
  }
  outrow((((TSTEPS + 7) & 1)) ? h2b1 : h2b0, TSTEPS + 7);
}

extern "C" void kernel_launch(void* const* d_in, const int* in_sizes, int n_in,
                              void* d_out, int out_size, void* d_ws, size_t ws_size,
                              hipStream_t stream) {
  Params P;
  P.input_t = (const float*)d_in[0];
  // d_in[1] = y : only its shape (T) matters; T hardcoded 512
  P.W_ih1 = (const float*)d_in[2];  P.b_ih1 = (const float*)d_in[3];
  P.W_hh1 = (const float*)d_in[4];  P.b_hh1 = (const float*)d_in[5];
  P.W_ih2 = (const float*)d_in[6];  P.b_ih2 = (const float*)d_in[7];
  P.W_hh2 = (const float*)d_in[8];  P.b_hh2 = (const float*)d_in[9];
  P.W_lin = (const float*)d_in[10]; P.b_lin = (const float*)d_in[11];
  P.out   = (float*)d_out;

  char* ws = (char*)d_ws;
  P.outfeed = (float*)(ws + 256);                  // 1 KB
  P.flags   = (unsigned*)(ws + 4096);              // 32 KB
  P.h1buf   = (half_t*)(ws + 4096 + 32768);        // [2][B][H] fp16 = 512 KB
  P.h2buf   = (half_t*)(ws + 4096 + 32768 + 2 * (size_t)HPLANE * sizeof(half_t));
  const size_t need = 4096 + 32768 + 4 * (size_t)HPLANE * sizeof(half_t);  // ~1.1 MB

  (void)hipMemsetAsync(d_ws, 0, need, stream);  // zero flags+outfeed+h buffers

  // PLAIN launch: grid == 256 CUs, 1 block/CU by resources => all resident.
  lstm_fused<<<dim3(WGS), dim3(NTHR), 0, stream>>>(P);
}